// Round 17
// baseline (773.749 us; speedup 1.0000x reference)
//
#include <hip/hip_runtime.h>
#include <hip/hip_bf16.h>
#include <cstdint>
#include <cstddef>

#define DEVI __device__ __forceinline__

typedef __attribute__((ext_vector_type(4))) float f32x4;
typedef __attribute__((ext_vector_type(2))) float f32x2;
typedef __attribute__((ext_vector_type(8))) short s16x8;
typedef __attribute__((ext_vector_type(4))) short s16x4;

constexpr int TB = 16;         // batch
constexpr int TT = 2048;       // time
constexpr int TD = 512;        // model dim
constexpr int TDFF = 2048;     // ffn dim
constexpr int NTOK = TB * TT;  // 32768
constexpr int KW = 31;         // conv kernel width
constexpr int CH = 16384;      // M-chunk (8 batches): big=64MB stays L3-resident
constexpr int NCHUNK = NTOK / CH;
constexpr int CT = 8;          // conv: tokens per block (38.9KB LDS -> 4 blk/CU)
constexpr int TR = CT + KW - 1; // 38 staged rows
constexpr int HCH = 64;        // hydra: token-chunks per batch (32 tokens each)

DEVI float b2f(unsigned short u) {
  union { float f; unsigned v; } x; x.v = ((unsigned)u) << 16; return x.f;
}
DEVI unsigned short f2bfb(float f) {
  __hip_bfloat16 h = __float2bfloat16(f);
  return __builtin_bit_cast(unsigned short, h);
}
DEVI float sigm(float x) { return 1.0f / (1.0f + __expf(-x)); }

DEVI void gload_lds16(const void* g, void* l) {
  __builtin_amdgcn_global_load_lds(
      (__attribute__((address_space(1))) unsigned int*)g,
      (__attribute__((address_space(3))) unsigned int*)l, 16, 0, 0);
}

DEVI f32x4 mfma_bf16(s16x8 a, s16x8 b, f32x4 c) {
  asm("v_mfma_f32_16x16x32_bf16 %0, %1, %2, %0" : "+v"(c) : "v"(a), "v"(b));
  return c;
}

// ---------------------------------------------------------------------------
// GEMM: C(Mrows,N) = A(.,K) x B(N,K)^T + bias  (A,B bf16 row-major)
// grid (M/128, N/128), x = row strip. T2 LDS swizzle (r14-proven, -48us).
// EPI 0: bf16(acc+bias) | 1: bf16(swish) | 2: bf16 residual add | 3: GLU pack
// bwbs: per-batch B stride in elements (0 = shared); batch = row0>>11.
// ---------------------------------------------------------------------------
template<int EPI, int RBF>
__global__ __launch_bounds__(256)
void gemm_bt(const __hip_bfloat16* __restrict__ A, const __hip_bfloat16* __restrict__ Bw,
             const float* __restrict__ bias, const void* resin,
             __hip_bfloat16* resout, __hip_bfloat16* __restrict__ outbf,
             int N, int K, float rscale, int bwbs)
{
  __shared__ alignas(16) short lds[2 * 128 * 64];
  short* As = lds;
  short* Bs = lds + 128 * 64;

  const int tid = threadIdx.x;
  const int w = tid >> 6, l = tid & 63;
  const int row0 = blockIdx.x * 128;
  const int col0 = blockIdx.y * 128;
  const __hip_bfloat16* Bwp = Bw + (size_t)(row0 >> 11) * bwbs;

  const int srow = w * 8 + (l >> 3);
  const int sce  = (((l & 7) * 16) ^ ((l >> 3) << 4)) >> 1;   // swizzled src col elem

  f32x4 acc[4][4];
#pragma unroll
  for (int m = 0; m < 4; ++m)
#pragma unroll
    for (int n = 0; n < 4; ++n)
      acc[m][n] = f32x4{0.f, 0.f, 0.f, 0.f};

  const int wr = (w >> 1) * 64, wc = (w & 1) * 64;
  const int xsw = (l & 7) << 4;

  for (int k0 = 0; k0 < K; k0 += 64) {
    __syncthreads();
#pragma unroll
    for (int it = 0; it < 4; ++it) {
      gload_lds16(A   + (size_t)(row0 + it * 32 + srow) * K + k0 + sce,
                  (char*)As + (it * 32 + w * 8) * 128);
      gload_lds16(Bwp + (size_t)(col0 + it * 32 + srow) * K + k0 + sce,
                  (char*)Bs + (it * 32 + w * 8) * 128);
    }
    __syncthreads();
#pragma unroll
    for (int ks = 0; ks < 2; ++ks) {
      const int ko = (ks * 64 + (l >> 4) * 16) ^ xsw;
      s16x8 af[4], bfr[4];
#pragma unroll
      for (int m = 0; m < 4; ++m)
        af[m] = *(const s16x8*)((const char*)As + (wr + m * 16 + (l & 15)) * 128 + ko);
#pragma unroll
      for (int n = 0; n < 4; ++n)
        bfr[n] = *(const s16x8*)((const char*)Bs + (wc + n * 16 + (l & 15)) * 128 + ko);
#pragma unroll
      for (int m = 0; m < 4; ++m)
#pragma unroll
        for (int n = 0; n < 4; ++n)
          acc[m][n] = mfma_bf16(bfr[n], af[m], acc[m][n]);   // swapped: row-major frag
    }
  }

  asm volatile("s_nop 7\n\ts_nop 7");

#pragma unroll
  for (int m = 0; m < 4; ++m) {
    const int grow = row0 + wr + m * 16 + (l & 15);
#pragma unroll
    for (int n = 0; n < 4; ++n) {
      const int gcol0 = col0 + wc + n * 16 + (l >> 4) * 4;
      const size_t idx = (size_t)grow * N + gcol0;
      const float4 bv = *(const float4*)(bias + gcol0);
      float vx = acc[m][n][0] + bv.x;
      float vy = acc[m][n][1] + bv.y;
      float vz = acc[m][n][2] + bv.z;
      float vw = acc[m][n][3] + bv.w;
      if constexpr (EPI == 0) {
        s16x4 p{(short)f2bfb(vx), (short)f2bfb(vy), (short)f2bfb(vz), (short)f2bfb(vw)};
        *(s16x4*)(outbf + idx) = p;
      } else if constexpr (EPI == 1) {
        vx *= sigm(vx); vy *= sigm(vy); vz *= sigm(vz); vw *= sigm(vw);
        s16x4 p{(short)f2bfb(vx), (short)f2bfb(vy), (short)f2bfb(vz), (short)f2bfb(vw)};
        *(s16x4*)(outbf + idx) = p;
      } else if constexpr (EPI == 3) {
        const unsigned short o0 = f2bfb(vx * sigm(vy));
        const unsigned short o1 = f2bfb(vz * sigm(vw));
        const int pv = (int)o0 | ((int)o1 << 16);
        *(int*)(outbf + (size_t)grow * (N >> 1) + (gcol0 >> 1)) = pv;
      } else {
        float r0, r1, r2, r3;
        if constexpr (RBF) {
          const s16x4 rv = *(const s16x4*)((const short*)resin + idx);
          r0 = b2f((unsigned short)rv[0]); r1 = b2f((unsigned short)rv[1]);
          r2 = b2f((unsigned short)rv[2]); r3 = b2f((unsigned short)rv[3]);
        } else {
          const float4 rv = *(const float4*)((const float*)resin + idx);
          r0 = rv.x; r1 = rv.y; r2 = rv.z; r3 = rv.w;
        }
        s16x4 p{(short)f2bfb(r0 + rscale * vx), (short)f2bfb(r1 + rscale * vy),
                (short)f2bfb(r2 + rscale * vz), (short)f2bfb(r3 + rscale * vw)};
        *(s16x4*)(resout + idx) = p;
      }
    }
  }
}

// ---------------------------------------------------------------------------
// gemm_bt64: 128x64 tile, grid (M/128, N/64), T2 swizzle. K=2048 N=512 GEMMs.
// ---------------------------------------------------------------------------
template<int EPI, int RBF>
__global__ __launch_bounds__(256)
void gemm_bt64(const __hip_bfloat16* __restrict__ A, const __hip_bfloat16* __restrict__ Bw,
               const float* __restrict__ bias, const void* resin,
               __hip_bfloat16* resout, __hip_bfloat16* __restrict__ outbf,
               int N, int K, float rscale)
{
  __shared__ alignas(16) short lds[192 * 64];
  short* As = lds;
  short* Bs = lds + 128 * 64;

  const int tid = threadIdx.x;
  const int w = tid >> 6, l = tid & 63;
  const int row0 = blockIdx.x * 128;
  const int col0 = blockIdx.y * 64;

  const int srow = w * 8 + (l >> 3);
  const int sce  = (((l & 7) * 16) ^ ((l >> 3) << 4)) >> 1;

  f32x4 acc[4][2];
#pragma unroll
  for (int m = 0; m < 4; ++m)
#pragma unroll
    for (int n = 0; n < 2; ++n)
      acc[m][n] = f32x4{0.f, 0.f, 0.f, 0.f};

  const int wr = (w >> 1) * 64, wc = (w & 1) * 32;
  const int xsw = (l & 7) << 4;

  for (int k0 = 0; k0 < K; k0 += 64) {
    __syncthreads();
#pragma unroll
    for (int it = 0; it < 4; ++it)
      gload_lds16(A + (size_t)(row0 + it * 32 + srow) * K + k0 + sce,
                  (char*)As + (it * 32 + w * 8) * 128);
#pragma unroll
    for (int it = 0; it < 2; ++it)
      gload_lds16(Bw + (size_t)(col0 + it * 32 + srow) * K + k0 + sce,
                  (char*)Bs + (it * 32 + w * 8) * 128);
    __syncthreads();
#pragma unroll
    for (int ks = 0; ks < 2; ++ks) {
      const int ko = (ks * 64 + (l >> 4) * 16) ^ xsw;
      s16x8 af[4], bfr[2];
#pragma unroll
      for (int m = 0; m < 4; ++m)
        af[m] = *(const s16x8*)((const char*)As + (wr + m * 16 + (l & 15)) * 128 + ko);
#pragma unroll
      for (int n = 0; n < 2; ++n)
        bfr[n] = *(const s16x8*)((const char*)Bs + (wc + n * 16 + (l & 15)) * 128 + ko);
#pragma unroll
      for (int m = 0; m < 4; ++m)
#pragma unroll
        for (int n = 0; n < 2; ++n)
          acc[m][n] = mfma_bf16(bfr[n], af[m], acc[m][n]);
    }
  }

  asm volatile("s_nop 7\n\ts_nop 7");

#pragma unroll
  for (int m = 0; m < 4; ++m) {
    const int grow = row0 + wr + m * 16 + (l & 15);
#pragma unroll
    for (int n = 0; n < 2; ++n) {
      const int gcol0 = col0 + wc + n * 16 + (l >> 4) * 4;
      const size_t idx = (size_t)grow * N + gcol0;
      const float4 bv = *(const float4*)(bias + gcol0);
      float vx = acc[m][n][0] + bv.x;
      float vy = acc[m][n][1] + bv.y;
      float vz = acc[m][n][2] + bv.z;
      float vw = acc[m][n][3] + bv.w;
      if constexpr (EPI == 0) {
        s16x4 p{(short)f2bfb(vx), (short)f2bfb(vy), (short)f2bfb(vz), (short)f2bfb(vw)};
        *(s16x4*)(outbf + idx) = p;
      } else if constexpr (EPI == 1) {
        vx *= sigm(vx); vy *= sigm(vy); vz *= sigm(vz); vw *= sigm(vw);
        s16x4 p{(short)f2bfb(vx), (short)f2bfb(vy), (short)f2bfb(vz), (short)f2bfb(vw)};
        *(s16x4*)(outbf + idx) = p;
      } else {
        float r0, r1, r2, r3;
        if constexpr (RBF) {
          const s16x4 rv = *(const s16x4*)((const short*)resin + idx);
          r0 = b2f((unsigned short)rv[0]); r1 = b2f((unsigned short)rv[1]);
          r2 = b2f((unsigned short)rv[2]); r3 = b2f((unsigned short)rv[3]);
        } else {
          const float4 rv = *(const float4*)((const float*)resin + idx);
          r0 = rv.x; r1 = rv.y; r2 = rv.z; r3 = rv.w;
        }
        s16x4 p{(short)f2bfb(r0 + rscale * vx), (short)f2bfb(r1 + rscale * vy),
                (short)f2bfb(r2 + rscale * vz), (short)f2bfb(r3 + rscale * vw)};
        *(s16x4*)(resout + idx) = p;
      }
    }
  }
}

// ---------------------------------------------------------------------------
// LayerNorm over D=512. One wave per token, 4 tokens/block.
// ---------------------------------------------------------------------------
template<int OUTF32, int INBF>
__global__ __launch_bounds__(256)
void ln_k(const void* __restrict__ xp, const float* __restrict__ g,
          const float* __restrict__ b, void* __restrict__ outp)
{
  const int w = threadIdx.x >> 6, l = threadIdx.x & 63;
  const size_t tok = (size_t)blockIdx.x * 4 + w;
  float v[8];
  if constexpr (INBF) {
    const s16x8 xv = ((const s16x8*)xp)[tok * 64 + l];
#pragma unroll
    for (int j = 0; j < 8; ++j) v[j] = b2f((unsigned short)xv[j]);
  } else {
    const float4* xr = (const float4*)xp + tok * 128;
    const float4 a = xr[2 * l], c = xr[2 * l + 1];
    v[0] = a.x; v[1] = a.y; v[2] = a.z; v[3] = a.w;
    v[4] = c.x; v[5] = c.y; v[6] = c.z; v[7] = c.w;
  }
  float s = 0.f, q = 0.f;
#pragma unroll
  for (int j = 0; j < 8; ++j) { s += v[j]; q += v[j] * v[j]; }
#pragma unroll
  for (int o = 32; o > 0; o >>= 1) { s += __shfl_xor(s, o); q += __shfl_xor(q, o); }
  const float mean = s * (1.f / TD);
  const float rs = rsqrtf(q * (1.f / TD) - mean * mean + 1e-5f);
  const float4 g0 = ((const float4*)g)[2 * l], g1 = ((const float4*)g)[2 * l + 1];
  const float4 b0 = ((const float4*)b)[2 * l], b1 = ((const float4*)b)[2 * l + 1];
  const float gg[8] = {g0.x, g0.y, g0.z, g0.w, g1.x, g1.y, g1.z, g1.w};
  const float bb[8] = {b0.x, b0.y, b0.z, b0.w, b1.x, b1.y, b1.z, b1.w};
  float o8[8];
#pragma unroll
  for (int j = 0; j < 8; ++j) o8[j] = (v[j] - mean) * rs * gg[j] + bb[j];
  if constexpr (OUTF32) {
    float4* out = (float4*)outp + tok * 128;
    out[2 * l]     = make_float4(o8[0], o8[1], o8[2], o8[3]);
    out[2 * l + 1] = make_float4(o8[4], o8[5], o8[6], o8[7]);
  } else {
    s16x8 p;
#pragma unroll
    for (int j = 0; j < 8; ++j) p[j] = (short)f2bfb(o8[j]);
    ((s16x8*)outp)[tok * 64 + l] = p;
  }
}

// ---------------------------------------------------------------------------
// Hydra pass1: 32 tokens/block, grid (CH/TT, HCH).
// ---------------------------------------------------------------------------
__global__ __launch_bounds__(256)
void hydra_pass1(const __hip_bfloat16* __restrict__ qkv,
                 __hip_bfloat16* __restrict__ qn,
                 float* __restrict__ kvpart, int b0)
{
  const int bl = blockIdx.x, ch = blockIdx.y;
  const int w = threadIdx.x >> 6, l = threadIdx.x & 63;
  float kvp[8] = {0.f, 0.f, 0.f, 0.f, 0.f, 0.f, 0.f, 0.f};
  __shared__ float part[4][512];

  for (int it = 0; it < 8; ++it) {
    const int t = ch * 32 + w * 8 + it;
    const short* row = (const short*)qkv + ((size_t)bl * TT + t) * (3 * TD);
    const s16x8 q8 = *(const s16x8*)(row + 8 * l);
    const s16x8 k8 = *(const s16x8*)(row + TD + 8 * l);
    const s16x8 v8 = *(const s16x8*)(row + 2 * TD + 8 * l);
    float qf[8], kf[8], vf[8];
    float sq = 0.f, sk = 0.f;
#pragma unroll
    for (int j = 0; j < 8; ++j) {
      qf[j] = b2f((unsigned short)q8[j]); sq += qf[j] * qf[j];
      kf[j] = b2f((unsigned short)k8[j]); sk += kf[j] * kf[j];
      vf[j] = b2f((unsigned short)v8[j]);
    }
#pragma unroll
    for (int o = 32; o > 0; o >>= 1) { sq += __shfl_xor(sq, o); sk += __shfl_xor(sk, o); }
    const float rq = rsqrtf(sq), rk = rsqrtf(sk);
    s16x8 r;
#pragma unroll
    for (int j = 0; j < 8; ++j) {
      r[j] = (short)f2bfb(qf[j] * rq);
      kvp[j] += kf[j] * rk * vf[j];
    }
    *(s16x8*)((short*)qn + ((size_t)bl * TT + t) * TD + 8 * l) = r;
  }
#pragma unroll
  for (int j = 0; j < 8; ++j) part[w][8 * l + j] = kvp[j];
  __syncthreads();
#pragma unroll
  for (int hh = 0; hh < 2; ++hh) {
    const int d = threadIdx.x + hh * 256;
    kvpart[((size_t)(b0 + bl) * HCH + ch) * TD + d]
        = part[0][d] + part[1][d] + part[2][d] + part[3][d];
  }
}

__global__ __launch_bounds__(256)
void kv_reduce(const float* __restrict__ kvpart, float* __restrict__ kv)
{
  const int i = blockIdx.x * 256 + threadIdx.x;
  const int b = i >> 9, d = i & 511;
  float s = 0.f;
#pragma unroll
  for (int ch = 0; ch < HCH; ++ch) s += kvpart[((size_t)b * HCH + ch) * TD + d];
  kv[i] = s;
}

// per-batch scaled attn-out weights: waob[b][n][k] = aow[n][k] * kv[b][k]
__global__ __launch_bounds__(256)
void wscale_k(const float* __restrict__ aow, const float* __restrict__ kv,
              __hip_bfloat16* __restrict__ waob)
{
  const size_t i8 = (size_t)blockIdx.x * 256 + threadIdx.x;   // 8 elems each
  const size_t i = i8 * 8;
  const int b = (int)(i >> 18);          // 512*512 per batch
  const int k = (int)(i & 511);
  const size_t wi = i & (size_t)(TD * TD - 1);
  const float4 w0 = *(const float4*)(aow + wi);
  const float4 w1 = *(const float4*)(aow + wi + 4);
  const float4 k0 = *(const float4*)(kv + b * TD + k);
  const float4 k1 = *(const float4*)(kv + b * TD + k + 4);
  s16x8 r;
  r[0] = (short)f2bfb(w0.x * k0.x);
  r[1] = (short)f2bfb(w0.y * k0.y);
  r[2] = (short)f2bfb(w0.z * k0.z);
  r[3] = (short)f2bfb(w0.w * k0.w);
  r[4] = (short)f2bfb(w1.x * k1.x);
  r[5] = (short)f2bfb(w1.y * k1.y);
  r[6] = (short)f2bfb(w1.z * k1.z);
  r[7] = (short)f2bfb(w1.w * k1.w);
  ((s16x8*)waob)[i8] = r;
}

// ---------------------------------------------------------------------------
// prep_all: merged prologue — y 0..5: f32->bf16 weight casts; y==6: pw1
// cast+interleave; y==7: dw transpose + pw1 bias pack. One dispatch.
// ---------------------------------------------------------------------------
struct PrepJobs {
  const float* src[6];
  __hip_bfloat16* dst[6];
  int n8[6];
  const float* pw1w; __hip_bfloat16* wpw1g;
  const float* dww;  float* dwt;
  const float* pw1b; float* pw1bg;
};
__global__ __launch_bounds__(256)
void prep_all(PrepJobs J)
{
  const int y = blockIdx.y;
  const int i = blockIdx.x * 256 + threadIdx.x;
  if (y < 6) {
    if (i >= J.n8[y]) return;
    const float4 a = ((const float4*)J.src[y])[2 * i];
    const float4 b = ((const float4*)J.src[y])[2 * i + 1];
    s16x8 r;
    r[0] = (short)f2bfb(a.x); r[1] = (short)f2bfb(a.y);
    r[2] = (short)f2bfb(a.z); r[3] = (short)f2bfb(a.w);
    r[4] = (short)f2bfb(b.x); r[5] = (short)f2bfb(b.y);
    r[6] = (short)f2bfb(b.z); r[7] = (short)f2bfb(b.w);
    ((s16x8*)J.dst[y])[i] = r;
  } else if (y == 6) {
    if (i >= 2 * TD * TD / 8) return;
    const int row = i >> 6, k8 = i & 63;
    const int d = row >> 1, s = row & 1;
    const float4* src = (const float4*)(J.pw1w + ((size_t)(s * TD + d)) * TD) + k8 * 2;
    const float4 a = src[0], b = src[1];
    s16x8 r;
    r[0] = (short)f2bfb(a.x); r[1] = (short)f2bfb(a.y);
    r[2] = (short)f2bfb(a.z); r[3] = (short)f2bfb(a.w);
    r[4] = (short)f2bfb(b.x); r[5] = (short)f2bfb(b.y);
    r[6] = (short)f2bfb(b.z); r[7] = (short)f2bfb(b.w);
    ((s16x8*)J.wpw1g)[(size_t)row * 64 + k8] = r;
  } else {
    if (i < KW * TD) {
      const int j = i / TD, d = i % TD;
      J.dwt[i] = J.dww[d * KW + j];
    } else if (i < KW * TD + 2 * TD) {
      const int j = i - KW * TD;
      J.pw1bg[j] = J.pw1b[(j & 1) * TD + (j >> 1)];
    }
  }
}

// ---------------------------------------------------------------------------
// conv7: depthwise conv(K=31,pad 15) + bias + LN + swish -> bf16.
// 512 thr, 1 ch/thread, CT=8 -> 38.9KB LDS -> 4 blocks/CU x 8 waves = 32
// waves/CU theoretical (2x conv6's resident waves). 4 independent FMA chains.
// ---------------------------------------------------------------------------
__global__ __launch_bounds__(512)
void conv7(const __hip_bfloat16* __restrict__ gin, const float* __restrict__ dwt,
           const float* __restrict__ dwb, const float* __restrict__ lg,
           const float* __restrict__ lb, __hip_bfloat16* __restrict__ out)
{
  const int b  = blockIdx.x / (TT / CT);
  const int t0 = (blockIdx.x % (TT / CT)) * CT;
  const int tid = threadIdx.x;
  const int w = tid >> 6, l = tid & 63;

  __shared__ alignas(16) short xs[TR][512];   // 38KB
  __shared__ float red[2][8][CT];

  for (int r = w; r < TR; r += 8) {
    const int tt = t0 + r - 15;
    if (tt >= 0 && tt < TT) {
      gload_lds16((const short*)gin + ((size_t)b * TT + tt) * TD + l * 8,
                  (char*)xs[r] + l * 16);
    } else {
      *(s16x8*)((char*)xs[r] + l * 16) = s16x8{0, 0, 0, 0, 0, 0, 0, 0};
    }
  }
  __syncthreads();   // drains vmcnt(0)+lgkmcnt(0) -> tile visible

  const int d = tid;
  float wreg[KW];
#pragma unroll
  for (int j = 0; j < KW; ++j) wreg[j] = dwt[j * TD + d];
  float xv[TR];
#pragma unroll
  for (int r = 0; r < TR; ++r) xv[r] = b2f((unsigned short)xs[r][d]);

  const float bv = dwb[d];
  float a[CT];
#pragma unroll
  for (int t = 0; t < CT; ++t) {
    float p0 = bv, p1 = 0.f, p2 = 0.f, p3 = 0.f;
#pragma unroll
    for (int j = 0; j < 8; ++j) {
      p0 += xv[t + j] * wreg[j];
      p1 += xv[t + 8 + j] * wreg[8 + j];
      p2 += xv[t + 16 + j] * wreg[16 + j];
      if (j < 7) p3 += xv[t + 24 + j] * wreg[24 + j];
    }
    a[t] = (p0 + p1) + (p2 + p3);
  }

#pragma unroll
  for (int t = 0; t < CT; ++t) {
    float ps = a[t], pq = a[t] * a[t];
#pragma unroll
    for (int o = 32; o > 0; o >>= 1) { ps += __shfl_xor(ps, o); pq += __shfl_xor(pq, o); }
    if (l == 0) { red[0][w][t] = ps; red[1][w][t] = pq; }
  }
  __syncthreads();
  const float gv = lg[d], bbv = lb[d];
#pragma unroll
  for (int t = 0; t < CT; ++t) {
    float s = 0.f, q = 0.f;
#pragma unroll
    for (int ww = 0; ww < 8; ++ww) { s += red[0][ww][t]; q += red[1][ww][t]; }
    const float mean = s * (1.f / TD);
    const float rs = rsqrtf(q * (1.f / TD) - mean * mean + 1e-5f);
    const float y = (a[t] - mean) * rs * gv + bbv;
    out[((size_t)b * TT + t0 + t) * TD + d] = __float2bfloat16(y * sigm(y));
  }
}

extern "C" void kernel_launch(void* const* d_in, const int* in_sizes, int n_in,
                              void* d_out, int out_size, void* d_ws, size_t ws_size,
                              hipStream_t stream)
{
  const float* x      = (const float*)d_in[0];
  const float* ln1_g  = (const float*)d_in[1];
  const float* ln1_b  = (const float*)d_in[2];
  const float* ff1_w1 = (const float*)d_in[3];
  const float* ff1_b1 = (const float*)d_in[4];
  const float* ff1_w2 = (const float*)d_in[5];
  const float* ff1_b2 = (const float*)d_in[6];
  const float* lna_g  = (const float*)d_in[7];
  const float* lna_b  = (const float*)d_in[8];
  const float* qkv_w  = (const float*)d_in[9];
  const float* qkv_b  = (const float*)d_in[10];
  const float* aow    = (const float*)d_in[11];
  const float* aob    = (const float*)d_in[12];
  const float* lnc_g  = (const float*)d_in[13];
  const float* lnc_b  = (const float*)d_in[14];
  const float* pw1_w  = (const float*)d_in[15];
  const float* pw1_b  = (const float*)d_in[16];
  const float* dw_w   = (const float*)d_in[17];
  const float* dw_b   = (const float*)d_in[18];
  const float* lncn_g = (const float*)d_in[19];
  const float* lncn_b = (const float*)d_in[20];
  const float* pw2_w  = (const float*)d_in[21];
  const float* pw2_b  = (const float*)d_in[22];
  const float* ln2_g  = (const float*)d_in[23];
  const float* ln2_b  = (const float*)d_in[24];
  const float* ff2_w1 = (const float*)d_in[25];
  const float* ff2_b1 = (const float*)d_in[26];
  const float* ff2_w2 = (const float*)d_in[27];
  const float* ff2_b2 = (const float*)d_in[28];
  const float* lno_g  = (const float*)d_in[29];
  const float* lno_b  = (const float*)d_in[30];
  (void)in_sizes; (void)n_in; (void)out_size;

  char* ws = (char*)d_ws;
  size_t off = 0;
  auto alloc = [&](size_t bytes) {
    char* p = ws + off;
    off = (off + bytes + 255) & ~(size_t)255;
    return p;
  };

  __hip_bfloat16* wff1a = (__hip_bfloat16*)alloc((size_t)TDFF * TD * 2);
  __hip_bfloat16* wff1b = (__hip_bfloat16*)alloc((size_t)TD * TDFF * 2);
  __hip_bfloat16* wqkv  = (__hip_bfloat16*)alloc((size_t)3 * TD * TD * 2);
  __hip_bfloat16* wpw1g = (__hip_bfloat16*)alloc((size_t)2 * TD * TD * 2);
  __hip_bfloat16* wpw2  = (__hip_bfloat16*)alloc((size_t)TD * TD * 2);
  __hip_bfloat16* wff2a = (__hip_bfloat16*)alloc((size_t)TDFF * TD * 2);
  __hip_bfloat16* wff2b = (__hip_bfloat16*)alloc((size_t)TD * TDFF * 2);
  __hip_bfloat16* waob  = (__hip_bfloat16*)alloc((size_t)TB * TD * TD * 2);  // 8MB
  __hip_bfloat16* h     = (__hip_bfloat16*)alloc((size_t)NTOK * TD * 2);     // 32MB
  __hip_bfloat16* big   = (__hip_bfloat16*)alloc((size_t)CH * TDFF * 2);     // 64MB
  __hip_bfloat16* resb  = (__hip_bfloat16*)alloc((size_t)NTOK * TD * 2);     // 32MB
  float*          kv    = (float*)alloc((size_t)TB * TD * 4);
  float*          kvp   = (float*)alloc((size_t)TB * HCH * TD * 4);          // 2MB
  float*          dwt   = (float*)alloc((size_t)KW * TD * 4);
  float*          pw1bg = (float*)alloc((size_t)2 * TD * 4);

  if (ws_size < off) return;   // interpretable failure instead of a page fault

  const dim3 blk(256), blk512(512);
  const int M = NTOK;

  PrepJobs J;
  J.src[0] = ff1_w1; J.dst[0] = wff1a; J.n8[0] = TDFF * TD / 8;
  J.src[1] = ff1_w2; J.dst[1] = wff1b; J.n8[1] = TD * TDFF / 8;
  J.src[2] = qkv_w;  J.dst[2] = wqkv;  J.n8[2] = 3 * TD * TD / 8;
  J.src[3] = pw2_w;  J.dst[3] = wpw2;  J.n8[3] = TD * TD / 8;
  J.src[4] = ff2_w1; J.dst[4] = wff2a; J.n8[4] = TDFF * TD / 8;
  J.src[5] = ff2_w2; J.dst[5] = wff2b; J.n8[5] = TD * TDFF / 8;
  J.pw1w = pw1_w; J.wpw1g = wpw1g;
  J.dww = dw_w;   J.dwt = dwt;
  J.pw1b = pw1_b; J.pw1bg = pw1bg;
  prep_all<<<dim3((TDFF * TD / 8 + 255) / 256, 8), blk, 0, stream>>>(J);

  // ---- FF1 (half-step): resb = bf16(x + 0.5*ffn(ln1(x))) ----
  ln_k<0, 0><<<M / 4, blk, 0, stream>>>(x, ln1_g, ln1_b, h);
  for (int c = 0; c < NCHUNK; ++c) {
    const size_t o5 = (size_t)c * CH * TD;
    gemm_bt<1, 0><<<dim3(CH / 128, TDFF / 128), blk, 0, stream>>>(
        h + o5, wff1a, ff1_b1, nullptr, nullptr, big, TDFF, TD, 0.f, 0);
    gemm_bt64<2, 0><<<dim3(CH / 128, TD / 64), blk, 0, stream>>>(
        big, wff1b, ff1_b2, x + o5, resb + o5, nullptr, TD, TDFF, 0.5f);
  }

  // ---- Hydra attention ----
  ln_k<0, 1><<<M / 4, blk, 0, stream>>>(resb, lna_g, lna_b, h);
  for (int c = 0; c < NCHUNK; ++c) {
    const size_t o5 = (size_t)c * CH * TD;
    gemm_bt<0, 0><<<dim3(CH / 128, 3 * TD / 128), blk, 0, stream>>>(
        h + o5, wqkv, qkv_b, nullptr, nullptr, big, 3 * TD, TD, 0.f, 0);
    hydra_pass1<<<dim3(CH / TT, HCH), blk, 0, stream>>>(big, h + o5, kvp, c * (CH / TT));
  }
  kv_reduce<<<(TB * TD) / 256, blk, 0, stream>>>(kvp, kv);
  wscale_k<<<(TB * TD * TD / 8) / 256, blk, 0, stream>>>(aow, kv, waob);
  gemm_bt<2, 1><<<dim3(M / 128, TD / 128), blk, 0, stream>>>(
      h, waob, aob, resb, resb, nullptr, TD, TD, 1.f, TD * TD);

  // ---- Conv module: PW1+GLU fused (interleaved weights) -> conv -> PW2 ----
  ln_k<0, 1><<<M / 4, blk, 0, stream>>>(resb, lnc_g, lnc_b, h);
  gemm_bt<3, 0><<<dim3(M / 128, 2 * TD / 128), blk, 0, stream>>>(
      h, wpw1g, pw1bg, nullptr, nullptr, big, 2 * TD, TD, 0.f, 0);
  conv7<<<TB * (TT / CT), blk512, 0, stream>>>(big, dwt, dw_b, lncn_g, lncn_b, h);
  gemm_bt<2, 1><<<dim3(M / 128, TD / 128), blk, 0, stream>>>(
      h, wpw2, pw2_b, resb, resb, nullptr, TD, TD, 1.f, 0);

  // ---- FF2 (half-step) ----
  ln_k<0, 1><<<M / 4, blk, 0, stream>>>(resb, ln2_g, ln2_b, h);
  for (int c = 0; c < NCHUNK; ++c) {
    const size_t o5 = (size_t)c * CH * TD;
    gemm_bt<1, 0><<<dim3(CH / 128, TDFF / 128), blk, 0, stream>>>(
        h + o5, wff2a, ff2_b1, nullptr, nullptr, big, TDFF, TD, 0.f, 0);
    gemm_bt64<2, 1><<<dim3(CH / 128, TD / 64), blk, 0, stream>>>(
        big, wff2b, ff2_b2, resb + o5, resb + o5, nullptr, TD, TDFF, 0.5f);
  }

  // ---- final LN: d_out(f32) = ln(resb) ----
  ln_k<1, 1><<<M / 4, blk, 0, stream>>>(resb, lno_g, lno_b, d_out);
}

// Round 18
// 723.929 us; speedup vs baseline: 1.0688x; 1.0688x over previous
//
#include <hip/hip_runtime.h>
#include <hip/hip_bf16.h>
#include <cstdint>
#include <cstddef>

#define DEVI __device__ __forceinline__

typedef __attribute__((ext_vector_type(4))) float f32x4;
typedef __attribute__((ext_vector_type(2))) float f32x2;
typedef __attribute__((ext_vector_type(8))) short s16x8;
typedef __attribute__((ext_vector_type(4))) short s16x4;

constexpr int TB = 16;         // batch
constexpr int TT = 2048;       // time
constexpr int TD = 512;        // model dim
constexpr int TDFF = 2048;     // ffn dim
constexpr int NTOK = TB * TT;  // 32768
constexpr int KW = 31;         // conv kernel width
constexpr int CH = 16384;      // M-chunk (8 batches): big=64MB stays L3-resident
constexpr int NCHUNK = NTOK / CH;
constexpr int CT = 8;          // conv: tokens per block (38KB LDS -> 4 blk/CU)
constexpr int TR = CT + KW - 1; // 38 staged rows
constexpr int HCH = 64;        // hydra: token-chunks per batch (32 tokens each)

DEVI float b2f(unsigned short u) {
  union { float f; unsigned v; } x; x.v = ((unsigned)u) << 16; return x.f;
}
DEVI unsigned short f2bfb(float f) {
  __hip_bfloat16 h = __float2bfloat16(f);
  return __builtin_bit_cast(unsigned short, h);
}
DEVI float sigm(float x) { return 1.0f / (1.0f + __expf(-x)); }

DEVI void gload_lds16(const void* g, void* l) {
  __builtin_amdgcn_global_load_lds(
      (__attribute__((address_space(1))) unsigned int*)g,
      (__attribute__((address_space(3))) unsigned int*)l, 16, 0, 0);
}

DEVI f32x4 mfma_bf16(s16x8 a, s16x8 b, f32x4 c) {
  asm("v_mfma_f32_16x16x32_bf16 %0, %1, %2, %0" : "+v"(c) : "v"(a), "v"(b));
  return c;
}

// ---------------------------------------------------------------------------
// GEMM: C(Mrows,N) = A(.,K) x B(N,K)^T + bias  (A,B bf16 row-major)
// grid (M/128, N/128), x = row strip. T2 LDS swizzle (r14-proven, -48us):
// linear LDS dest, global SOURCE col pre-swizzled ^((row&7)<<4), ds_read col
// swizzled by the same XOR.
// EPI 0: bf16(acc+bias) | 1: bf16(swish) | 2: bf16 residual add | 3: GLU pack
// bwbs: per-batch B stride in elements (0 = shared); batch = row0>>11.
// ---------------------------------------------------------------------------
template<int EPI, int RBF>
__global__ __launch_bounds__(256)
void gemm_bt(const __hip_bfloat16* __restrict__ A, const __hip_bfloat16* __restrict__ Bw,
             const float* __restrict__ bias, const void* resin,
             __hip_bfloat16* resout, __hip_bfloat16* __restrict__ outbf,
             int N, int K, float rscale, int bwbs)
{
  __shared__ alignas(16) short lds[2 * 128 * 64];
  short* As = lds;
  short* Bs = lds + 128 * 64;

  const int tid = threadIdx.x;
  const int w = tid >> 6, l = tid & 63;
  const int row0 = blockIdx.x * 128;
  const int col0 = blockIdx.y * 128;
  const __hip_bfloat16* Bwp = Bw + (size_t)(row0 >> 11) * bwbs;

  const int srow = w * 8 + (l >> 3);
  const int sce  = (((l & 7) * 16) ^ ((l >> 3) << 4)) >> 1;   // swizzled src col elem

  f32x4 acc[4][4];
#pragma unroll
  for (int m = 0; m < 4; ++m)
#pragma unroll
    for (int n = 0; n < 4; ++n)
      acc[m][n] = f32x4{0.f, 0.f, 0.f, 0.f};

  const int wr = (w >> 1) * 64, wc = (w & 1) * 64;
  const int xsw = (l & 7) << 4;

  for (int k0 = 0; k0 < K; k0 += 64) {
    __syncthreads();
#pragma unroll
    for (int it = 0; it < 4; ++it) {
      gload_lds16(A   + (size_t)(row0 + it * 32 + srow) * K + k0 + sce,
                  (char*)As + (it * 32 + w * 8) * 128);
      gload_lds16(Bwp + (size_t)(col0 + it * 32 + srow) * K + k0 + sce,
                  (char*)Bs + (it * 32 + w * 8) * 128);
    }
    __syncthreads();
#pragma unroll
    for (int ks = 0; ks < 2; ++ks) {
      const int ko = (ks * 64 + (l >> 4) * 16) ^ xsw;
      s16x8 af[4], bfr[4];
#pragma unroll
      for (int m = 0; m < 4; ++m)
        af[m] = *(const s16x8*)((const char*)As + (wr + m * 16 + (l & 15)) * 128 + ko);
#pragma unroll
      for (int n = 0; n < 4; ++n)
        bfr[n] = *(const s16x8*)((const char*)Bs + (wc + n * 16 + (l & 15)) * 128 + ko);
#pragma unroll
      for (int m = 0; m < 4; ++m)
#pragma unroll
        for (int n = 0; n < 4; ++n)
          acc[m][n] = mfma_bf16(bfr[n], af[m], acc[m][n]);   // swapped: row-major frag
    }
  }

  asm volatile("s_nop 7\n\ts_nop 7");

#pragma unroll
  for (int m = 0; m < 4; ++m) {
    const int grow = row0 + wr + m * 16 + (l & 15);
#pragma unroll
    for (int n = 0; n < 4; ++n) {
      const int gcol0 = col0 + wc + n * 16 + (l >> 4) * 4;
      const size_t idx = (size_t)grow * N + gcol0;
      const float4 bv = *(const float4*)(bias + gcol0);
      float vx = acc[m][n][0] + bv.x;
      float vy = acc[m][n][1] + bv.y;
      float vz = acc[m][n][2] + bv.z;
      float vw = acc[m][n][3] + bv.w;
      if constexpr (EPI == 0) {
        s16x4 p{(short)f2bfb(vx), (short)f2bfb(vy), (short)f2bfb(vz), (short)f2bfb(vw)};
        *(s16x4*)(outbf + idx) = p;
      } else if constexpr (EPI == 1) {
        vx *= sigm(vx); vy *= sigm(vy); vz *= sigm(vz); vw *= sigm(vw);
        s16x4 p{(short)f2bfb(vx), (short)f2bfb(vy), (short)f2bfb(vz), (short)f2bfb(vw)};
        *(s16x4*)(outbf + idx) = p;
      } else if constexpr (EPI == 3) {
        const unsigned short o0 = f2bfb(vx * sigm(vy));
        const unsigned short o1 = f2bfb(vz * sigm(vw));
        const int pv = (int)o0 | ((int)o1 << 16);
        *(int*)(outbf + (size_t)grow * (N >> 1) + (gcol0 >> 1)) = pv;
      } else {
        float r0, r1, r2, r3;
        if constexpr (RBF) {
          const s16x4 rv = *(const s16x4*)((const short*)resin + idx);
          r0 = b2f((unsigned short)rv[0]); r1 = b2f((unsigned short)rv[1]);
          r2 = b2f((unsigned short)rv[2]); r3 = b2f((unsigned short)rv[3]);
        } else {
          const float4 rv = *(const float4*)((const float*)resin + idx);
          r0 = rv.x; r1 = rv.y; r2 = rv.z; r3 = rv.w;
        }
        s16x4 p{(short)f2bfb(r0 + rscale * vx), (short)f2bfb(r1 + rscale * vy),
                (short)f2bfb(r2 + rscale * vz), (short)f2bfb(r3 + rscale * vw)};
        *(s16x4*)(resout + idx) = p;
      }
    }
  }
}

// ---------------------------------------------------------------------------
// gemm_bt64: 128x64 tile, grid (M/128, N/64), T2 swizzle. K=2048 N=512 GEMMs.
// ---------------------------------------------------------------------------
template<int EPI, int RBF>
__global__ __launch_bounds__(256)
void gemm_bt64(const __hip_bfloat16* __restrict__ A, const __hip_bfloat16* __restrict__ Bw,
               const float* __restrict__ bias, const void* resin,
               __hip_bfloat16* resout, __hip_bfloat16* __restrict__ outbf,
               int N, int K, float rscale)
{
  __shared__ alignas(16) short lds[192 * 64];
  short* As = lds;
  short* Bs = lds + 128 * 64;

  const int tid = threadIdx.x;
  const int w = tid >> 6, l = tid & 63;
  const int row0 = blockIdx.x * 128;
  const int col0 = blockIdx.y * 64;

  const int srow = w * 8 + (l >> 3);
  const int sce  = (((l & 7) * 16) ^ ((l >> 3) << 4)) >> 1;

  f32x4 acc[4][2];
#pragma unroll
  for (int m = 0; m < 4; ++m)
#pragma unroll
    for (int n = 0; n < 2; ++n)
      acc[m][n] = f32x4{0.f, 0.f, 0.f, 0.f};

  const int wr = (w >> 1) * 64, wc = (w & 1) * 32;
  const int xsw = (l & 7) << 4;

  for (int k0 = 0; k0 < K; k0 += 64) {
    __syncthreads();
#pragma unroll
    for (int it = 0; it < 4; ++it)
      gload_lds16(A + (size_t)(row0 + it * 32 + srow) * K + k0 + sce,
                  (char*)As + (it * 32 + w * 8) * 128);
#pragma unroll
    for (int it = 0; it < 2; ++it)
      gload_lds16(Bw + (size_t)(col0 + it * 32 + srow) * K + k0 + sce,
                  (char*)Bs + (it * 32 + w * 8) * 128);
    __syncthreads();
#pragma unroll
    for (int ks = 0; ks < 2; ++ks) {
      const int ko = (ks * 64 + (l >> 4) * 16) ^ xsw;
      s16x8 af[4], bfr[2];
#pragma unroll
      for (int m = 0; m < 4; ++m)
        af[m] = *(const s16x8*)((const char*)As + (wr + m * 16 + (l & 15)) * 128 + ko);
#pragma unroll
      for (int n = 0; n < 2; ++n)
        bfr[n] = *(const s16x8*)((const char*)Bs + (wc + n * 16 + (l & 15)) * 128 + ko);
#pragma unroll
      for (int m = 0; m < 4; ++m)
#pragma unroll
        for (int n = 0; n < 2; ++n)
          acc[m][n] = mfma_bf16(bfr[n], af[m], acc[m][n]);
    }
  }

  asm volatile("s_nop 7\n\ts_nop 7");

#pragma unroll
  for (int m = 0; m < 4; ++m) {
    const int grow = row0 + wr + m * 16 + (l & 15);
#pragma unroll
    for (int n = 0; n < 2; ++n) {
      const int gcol0 = col0 + wc + n * 16 + (l >> 4) * 4;
      const size_t idx = (size_t)grow * N + gcol0;
      const float4 bv = *(const float4*)(bias + gcol0);
      float vx = acc[m][n][0] + bv.x;
      float vy = acc[m][n][1] + bv.y;
      float vz = acc[m][n][2] + bv.z;
      float vw = acc[m][n][3] + bv.w;
      if constexpr (EPI == 0) {
        s16x4 p{(short)f2bfb(vx), (short)f2bfb(vy), (short)f2bfb(vz), (short)f2bfb(vw)};
        *(s16x4*)(outbf + idx) = p;
      } else if constexpr (EPI == 1) {
        vx *= sigm(vx); vy *= sigm(vy); vz *= sigm(vz); vw *= sigm(vw);
        s16x4 p{(short)f2bfb(vx), (short)f2bfb(vy), (short)f2bfb(vz), (short)f2bfb(vw)};
        *(s16x4*)(outbf + idx) = p;
      } else {
        float r0, r1, r2, r3;
        if constexpr (RBF) {
          const s16x4 rv = *(const s16x4*)((const short*)resin + idx);
          r0 = b2f((unsigned short)rv[0]); r1 = b2f((unsigned short)rv[1]);
          r2 = b2f((unsigned short)rv[2]); r3 = b2f((unsigned short)rv[3]);
        } else {
          const float4 rv = *(const float4*)((const float*)resin + idx);
          r0 = rv.x; r1 = rv.y; r2 = rv.z; r3 = rv.w;
        }
        s16x4 p{(short)f2bfb(r0 + rscale * vx), (short)f2bfb(r1 + rscale * vy),
                (short)f2bfb(r2 + rscale * vz), (short)f2bfb(r3 + rscale * vw)};
        *(s16x4*)(resout + idx) = p;
      }
    }
  }
}

// ---------------------------------------------------------------------------
// LayerNorm over D=512. One wave per token, 4 tokens/block.
// ---------------------------------------------------------------------------
template<int OUTF32, int INBF>
__global__ __launch_bounds__(256)
void ln_k(const void* __restrict__ xp, const float* __restrict__ g,
          const float* __restrict__ b, void* __restrict__ outp)
{
  const int w = threadIdx.x >> 6, l = threadIdx.x & 63;
  const size_t tok = (size_t)blockIdx.x * 4 + w;
  float v[8];
  if constexpr (INBF) {
    const s16x8 xv = ((const s16x8*)xp)[tok * 64 + l];
#pragma unroll
    for (int j = 0; j < 8; ++j) v[j] = b2f((unsigned short)xv[j]);
  } else {
    const float4* xr = (const float4*)xp + tok * 128;
    const float4 a = xr[2 * l], c = xr[2 * l + 1];
    v[0] = a.x; v[1] = a.y; v[2] = a.z; v[3] = a.w;
    v[4] = c.x; v[5] = c.y; v[6] = c.z; v[7] = c.w;
  }
  float s = 0.f, q = 0.f;
#pragma unroll
  for (int j = 0; j < 8; ++j) { s += v[j]; q += v[j] * v[j]; }
#pragma unroll
  for (int o = 32; o > 0; o >>= 1) { s += __shfl_xor(s, o); q += __shfl_xor(q, o); }
  const float mean = s * (1.f / TD);
  const float rs = rsqrtf(q * (1.f / TD) - mean * mean + 1e-5f);
  const float4 g0 = ((const float4*)g)[2 * l], g1 = ((const float4*)g)[2 * l + 1];
  const float4 b0 = ((const float4*)b)[2 * l], b1 = ((const float4*)b)[2 * l + 1];
  const float gg[8] = {g0.x, g0.y, g0.z, g0.w, g1.x, g1.y, g1.z, g1.w};
  const float bb[8] = {b0.x, b0.y, b0.z, b0.w, b1.x, b1.y, b1.z, b1.w};
  float o8[8];
#pragma unroll
  for (int j = 0; j < 8; ++j) o8[j] = (v[j] - mean) * rs * gg[j] + bb[j];
  if constexpr (OUTF32) {
    float4* out = (float4*)outp + tok * 128;
    out[2 * l]     = make_float4(o8[0], o8[1], o8[2], o8[3]);
    out[2 * l + 1] = make_float4(o8[4], o8[5], o8[6], o8[7]);
  } else {
    s16x8 p;
#pragma unroll
    for (int j = 0; j < 8; ++j) p[j] = (short)f2bfb(o8[j]);
    ((s16x8*)outp)[tok * 64 + l] = p;
  }
}

// ---------------------------------------------------------------------------
// Hydra pass1: 32 tokens/block, grid (CH/TT, HCH).
// ---------------------------------------------------------------------------
__global__ __launch_bounds__(256)
void hydra_pass1(const __hip_bfloat16* __restrict__ qkv,
                 __hip_bfloat16* __restrict__ qn,
                 float* __restrict__ kvpart, int b0)
{
  const int bl = blockIdx.x, ch = blockIdx.y;
  const int w = threadIdx.x >> 6, l = threadIdx.x & 63;
  float kvp[8] = {0.f, 0.f, 0.f, 0.f, 0.f, 0.f, 0.f, 0.f};
  __shared__ float part[4][512];

  for (int it = 0; it < 8; ++it) {
    const int t = ch * 32 + w * 8 + it;
    const short* row = (const short*)qkv + ((size_t)bl * TT + t) * (3 * TD);
    const s16x8 q8 = *(const s16x8*)(row + 8 * l);
    const s16x8 k8 = *(const s16x8*)(row + TD + 8 * l);
    const s16x8 v8 = *(const s16x8*)(row + 2 * TD + 8 * l);
    float qf[8], kf[8], vf[8];
    float sq = 0.f, sk = 0.f;
#pragma unroll
    for (int j = 0; j < 8; ++j) {
      qf[j] = b2f((unsigned short)q8[j]); sq += qf[j] * qf[j];
      kf[j] = b2f((unsigned short)k8[j]); sk += kf[j] * kf[j];
      vf[j] = b2f((unsigned short)v8[j]);
    }
#pragma unroll
    for (int o = 32; o > 0; o >>= 1) { sq += __shfl_xor(sq, o); sk += __shfl_xor(sk, o); }
    const float rq = rsqrtf(sq), rk = rsqrtf(sk);
    s16x8 r;
#pragma unroll
    for (int j = 0; j < 8; ++j) {
      r[j] = (short)f2bfb(qf[j] * rq);
      kvp[j] += kf[j] * rk * vf[j];
    }
    *(s16x8*)((short*)qn + ((size_t)bl * TT + t) * TD + 8 * l) = r;
  }
#pragma unroll
  for (int j = 0; j < 8; ++j) part[w][8 * l + j] = kvp[j];
  __syncthreads();
#pragma unroll
  for (int hh = 0; hh < 2; ++hh) {
    const int d = threadIdx.x + hh * 256;
    kvpart[((size_t)(b0 + bl) * HCH + ch) * TD + d]
        = part[0][d] + part[1][d] + part[2][d] + part[3][d];
  }
}

__global__ __launch_bounds__(256)
void kv_reduce(const float* __restrict__ kvpart, float* __restrict__ kv)
{
  const int i = blockIdx.x * 256 + threadIdx.x;
  const int b = i >> 9, d = i & 511;
  float s = 0.f;
#pragma unroll
  for (int ch = 0; ch < HCH; ++ch) s += kvpart[((size_t)b * HCH + ch) * TD + d];
  kv[i] = s;
}

// per-batch scaled attn-out weights: waob[b][n][k] = aow[n][k] * kv[b][k]
__global__ __launch_bounds__(256)
void wscale_k(const float* __restrict__ aow, const float* __restrict__ kv,
              __hip_bfloat16* __restrict__ waob)
{
  const size_t i8 = (size_t)blockIdx.x * 256 + threadIdx.x;   // 8 elems each
  const size_t i = i8 * 8;
  const int b = (int)(i >> 18);          // 512*512 per batch
  const int k = (int)(i & 511);
  const size_t wi = i & (size_t)(TD * TD - 1);
  const float4 w0 = *(const float4*)(aow + wi);
  const float4 w1 = *(const float4*)(aow + wi + 4);
  const float4 k0 = *(const float4*)(kv + b * TD + k);
  const float4 k1 = *(const float4*)(kv + b * TD + k + 4);
  s16x8 r;
  r[0] = (short)f2bfb(w0.x * k0.x);
  r[1] = (short)f2bfb(w0.y * k0.y);
  r[2] = (short)f2bfb(w0.z * k0.z);
  r[3] = (short)f2bfb(w0.w * k0.w);
  r[4] = (short)f2bfb(w1.x * k1.x);
  r[5] = (short)f2bfb(w1.y * k1.y);
  r[6] = (short)f2bfb(w1.z * k1.z);
  r[7] = (short)f2bfb(w1.w * k1.w);
  ((s16x8*)waob)[i8] = r;
}

// ---------------------------------------------------------------------------
// prep_all: merged prologue — y 0..5: f32->bf16 weight casts; y==6: pw1
// cast+interleave; y==7: dw transpose + pw1 bias pack. One dispatch.
// ---------------------------------------------------------------------------
struct PrepJobs {
  const float* src[6];
  __hip_bfloat16* dst[6];
  int n8[6];
  const float* pw1w; __hip_bfloat16* wpw1g;
  const float* dww;  float* dwt;
  const float* pw1b; float* pw1bg;
};
__global__ __launch_bounds__(256)
void prep_all(PrepJobs J)
{
  const int y = blockIdx.y;
  const int i = blockIdx.x * 256 + threadIdx.x;
  if (y < 6) {
    if (i >= J.n8[y]) return;
    const float4 a = ((const float4*)J.src[y])[2 * i];
    const float4 b = ((const float4*)J.src[y])[2 * i + 1];
    s16x8 r;
    r[0] = (short)f2bfb(a.x); r[1] = (short)f2bfb(a.y);
    r[2] = (short)f2bfb(a.z); r[3] = (short)f2bfb(a.w);
    r[4] = (short)f2bfb(b.x); r[5] = (short)f2bfb(b.y);
    r[6] = (short)f2bfb(b.z); r[7] = (short)f2bfb(b.w);
    ((s16x8*)J.dst[y])[i] = r;
  } else if (y == 6) {
    if (i >= 2 * TD * TD / 8) return;
    const int row = i >> 6, k8 = i & 63;
    const int d = row >> 1, s = row & 1;
    const float4* src = (const float4*)(J.pw1w + ((size_t)(s * TD + d)) * TD) + k8 * 2;
    const float4 a = src[0], b = src[1];
    s16x8 r;
    r[0] = (short)f2bfb(a.x); r[1] = (short)f2bfb(a.y);
    r[2] = (short)f2bfb(a.z); r[3] = (short)f2bfb(a.w);
    r[4] = (short)f2bfb(b.x); r[5] = (short)f2bfb(b.y);
    r[6] = (short)f2bfb(b.z); r[7] = (short)f2bfb(b.w);
    ((s16x8*)J.wpw1g)[(size_t)row * 64 + k8] = r;
  } else {
    if (i < KW * TD) {
      const int j = i / TD, d = i % TD;
      J.dwt[i] = J.dww[d * KW + j];
    } else if (i < KW * TD + 2 * TD) {
      const int j = i - KW * TD;
      J.pw1bg[j] = J.pw1b[(j & 1) * TD + (j >> 1)];
    }
  }
}

// ---------------------------------------------------------------------------
// conv6: depthwise conv(K=31,pad 15) + bias + LN + swish -> bf16.
// 256 thr, 2 adjacent channels/thread, CT=8 tokens -> TR=38 rows = 38KB LDS
// -> 4 blocks/CU. Instruction-economy structure (b32 LDS reads, packed math,
// 4B stores) — r16-proven best conv (73us).
// ---------------------------------------------------------------------------
__global__ __launch_bounds__(256)
void conv6(const __hip_bfloat16* __restrict__ gin, const float* __restrict__ dwt,
           const float* __restrict__ dwb, const float* __restrict__ lg,
           const float* __restrict__ lb, __hip_bfloat16* __restrict__ out)
{
  const int b  = blockIdx.x / (TT / CT);
  const int t0 = (blockIdx.x % (TT / CT)) * CT;
  const int tid = threadIdx.x;
  const int w = tid >> 6, l = tid & 63;

  __shared__ alignas(16) short xs[TR][512];   // 38KB
  __shared__ float red[2][4][CT];

  for (int r = w; r < TR; r += 4) {
    const int tt = t0 + r - 15;
    if (tt >= 0 && tt < TT) {
      gload_lds16((const short*)gin + ((size_t)b * TT + tt) * TD + l * 8,
                  (char*)xs[r] + l * 16);
    } else {
      *(s16x8*)((char*)xs[r] + l * 16) = s16x8{0, 0, 0, 0, 0, 0, 0, 0};
    }
  }
  __syncthreads();   // drains vmcnt(0)+lgkmcnt(0) -> tile visible

  const int d0 = tid * 2;   // channel pair (d0, d0+1)
  f32x2 wreg[KW];
#pragma unroll
  for (int j = 0; j < KW; ++j) wreg[j] = *(const f32x2*)(dwt + j * TD + d0);

  f32x2 xv[TR];
#pragma unroll
  for (int r = 0; r < TR; ++r) {
    const unsigned v = *(const unsigned*)&xs[r][d0];     // 1 ds_read_b32 = 2 ch
    xv[r] = f32x2{__builtin_bit_cast(float, v << 16),
                  __builtin_bit_cast(float, v & 0xffff0000u)};
  }

  const f32x2 bv = *(const f32x2*)(dwb + d0);
  f32x2 a[CT];
#pragma unroll
  for (int t = 0; t < CT; ++t) {
    f32x2 p0 = bv, p1 = {0.f, 0.f}, p2 = {0.f, 0.f}, p3 = {0.f, 0.f};
#pragma unroll
    for (int j = 0; j < 8; ++j) {
      p0 += xv[t + j] * wreg[j];
      p1 += xv[t + 8 + j] * wreg[8 + j];
      p2 += xv[t + 16 + j] * wreg[16 + j];
      if (j < 7) p3 += xv[t + 24 + j] * wreg[24 + j];
    }
    a[t] = (p0 + p1) + (p2 + p3);
  }

#pragma unroll
  for (int t = 0; t < CT; ++t) {
    float ps = a[t].x + a[t].y;
    float pq = a[t].x * a[t].x + a[t].y * a[t].y;
#pragma unroll
    for (int o = 32; o > 0; o >>= 1) { ps += __shfl_xor(ps, o); pq += __shfl_xor(pq, o); }
    if (l == 0) { red[0][w][t] = ps; red[1][w][t] = pq; }
  }
  __syncthreads();
  const f32x2 gv = *(const f32x2*)(lg + d0);
  const f32x2 bbv = *(const f32x2*)(lb + d0);
#pragma unroll
  for (int t = 0; t < CT; ++t) {
    const float s = red[0][0][t] + red[0][1][t] + red[0][2][t] + red[0][3][t];
    const float q = red[1][0][t] + red[1][1][t] + red[1][2][t] + red[1][3][t];
    const float mean = s * (1.f / TD);
    const float rs = rsqrtf(q * (1.f / TD) - mean * mean + 1e-5f);
    const float y0 = (a[t].x - mean) * rs * gv.x + bbv.x;
    const float y1 = (a[t].y - mean) * rs * gv.y + bbv.y;
    const unsigned short o0 = f2bfb(y0 * sigm(y0));
    const unsigned short o1 = f2bfb(y1 * sigm(y1));
    const unsigned pv = (unsigned)o0 | ((unsigned)o1 << 16);
    *(unsigned*)((short*)out + ((size_t)b * TT + t0 + t) * TD + d0) = pv;
  }
}

extern "C" void kernel_launch(void* const* d_in, const int* in_sizes, int n_in,
                              void* d_out, int out_size, void* d_ws, size_t ws_size,
                              hipStream_t stream)
{
  const float* x      = (const float*)d_in[0];
  const float* ln1_g  = (const float*)d_in[1];
  const float* ln1_b  = (const float*)d_in[2];
  const float* ff1_w1 = (const float*)d_in[3];
  const float* ff1_b1 = (const float*)d_in[4];
  const float* ff1_w2 = (const float*)d_in[5];
  const float* ff1_b2 = (const float*)d_in[6];
  const float* lna_g  = (const float*)d_in[7];
  const float* lna_b  = (const float*)d_in[8];
  const float* qkv_w  = (const float*)d_in[9];
  const float* qkv_b  = (const float*)d_in[10];
  const float* aow    = (const float*)d_in[11];
  const float* aob    = (const float*)d_in[12];
  const float* lnc_g  = (const float*)d_in[13];
  const float* lnc_b  = (const float*)d_in[14];
  const float* pw1_w  = (const float*)d_in[15];
  const float* pw1_b  = (const float*)d_in[16];
  const float* dw_w   = (const float*)d_in[17];
  const float* dw_b   = (const float*)d_in[18];
  const float* lncn_g = (const float*)d_in[19];
  const float* lncn_b = (const float*)d_in[20];
  const float* pw2_w  = (const float*)d_in[21];
  const float* pw2_b  = (const float*)d_in[22];
  const float* ln2_g  = (const float*)d_in[23];
  const float* ln2_b  = (const float*)d_in[24];
  const float* ff2_w1 = (const float*)d_in[25];
  const float* ff2_b1 = (const float*)d_in[26];
  const float* ff2_w2 = (const float*)d_in[27];
  const float* ff2_b2 = (const float*)d_in[28];
  const float* lno_g  = (const float*)d_in[29];
  const float* lno_b  = (const float*)d_in[30];
  (void)in_sizes; (void)n_in; (void)out_size;

  char* ws = (char*)d_ws;
  size_t off = 0;
  auto alloc = [&](size_t bytes) {
    char* p = ws + off;
    off = (off + bytes + 255) & ~(size_t)255;
    return p;
  };

  __hip_bfloat16* wff1a = (__hip_bfloat16*)alloc((size_t)TDFF * TD * 2);
  __hip_bfloat16* wff1b = (__hip_bfloat16*)alloc((size_t)TD * TDFF * 2);
  __hip_bfloat16* wqkv  = (__hip_bfloat16*)alloc((size_t)3 * TD * TD * 2);
  __hip_bfloat16* wpw1g = (__hip_bfloat16*)alloc((size_t)2 * TD * TD * 2);
  __hip_bfloat16* wpw2  = (__hip_bfloat16*)alloc((size_t)TD * TD * 2);
  __hip_bfloat16* wff2a = (__hip_bfloat16*)alloc((size_t)TDFF * TD * 2);
  __hip_bfloat16* wff2b = (__hip_bfloat16*)alloc((size_t)TD * TDFF * 2);
  __hip_bfloat16* waob  = (__hip_bfloat16*)alloc((size_t)TB * TD * TD * 2);  // 8MB
  __hip_bfloat16* h     = (__hip_bfloat16*)alloc((size_t)NTOK * TD * 2);     // 32MB
  __hip_bfloat16* big   = (__hip_bfloat16*)alloc((size_t)CH * TDFF * 2);     // 64MB
  __hip_bfloat16* resb  = (__hip_bfloat16*)alloc((size_t)NTOK * TD * 2);     // 32MB
  float*          kv    = (float*)alloc((size_t)TB * TD * 4);
  float*          kvp   = (float*)alloc((size_t)TB * HCH * TD * 4);          // 2MB
  float*          dwt   = (float*)alloc((size_t)KW * TD * 4);
  float*          pw1bg = (float*)alloc((size_t)2 * TD * 4);

  if (ws_size < off) return;   // interpretable failure instead of a page fault

  const dim3 blk(256);
  const int M = NTOK;

  PrepJobs J;
  J.src[0] = ff1_w1; J.dst[0] = wff1a; J.n8[0] = TDFF * TD / 8;
  J.src[1] = ff1_w2; J.dst[1] = wff1b; J.n8[1] = TD * TDFF / 8;
  J.src[2] = qkv_w;  J.dst[2] = wqkv;  J.n8[2] = 3 * TD * TD / 8;
  J.src[3] = pw2_w;  J.dst[3] = wpw2;  J.n8[3] = TD * TD / 8;
  J.src[4] = ff2_w1; J.dst[4] = wff2a; J.n8[4] = TDFF * TD / 8;
  J.src[5] = ff2_w2; J.dst[5] = wff2b; J.n8[5] = TD * TDFF / 8;
  J.pw1w = pw1_w; J.wpw1g = wpw1g;
  J.dww = dw_w;   J.dwt = dwt;
  J.pw1b = pw1_b; J.pw1bg = pw1bg;
  prep_all<<<dim3((TDFF * TD / 8 + 255) / 256, 8), blk, 0, stream>>>(J);

  // ---- FF1 (half-step): resb = bf16(x + 0.5*ffn(ln1(x))) ----
  ln_k<0, 0><<<M / 4, blk, 0, stream>>>(x, ln1_g, ln1_b, h);
  for (int c = 0; c < NCHUNK; ++c) {
    const size_t o5 = (size_t)c * CH * TD;
    gemm_bt<1, 0><<<dim3(CH / 128, TDFF / 128), blk, 0, stream>>>(
        h + o5, wff1a, ff1_b1, nullptr, nullptr, big, TDFF, TD, 0.f, 0);
    gemm_bt64<2, 0><<<dim3(CH / 128, TD / 64), blk, 0, stream>>>(
        big, wff1b, ff1_b2, x + o5, resb + o5, nullptr, TD, TDFF, 0.5f);
  }

  // ---- Hydra attention ----
  ln_k<0, 1><<<M / 4, blk, 0, stream>>>(resb, lna_g, lna_b, h);
  for (int c = 0; c < NCHUNK; ++c) {
    const size_t o5 = (size_t)c * CH * TD;
    gemm_bt<0, 0><<<dim3(CH / 128, 3 * TD / 128), blk, 0, stream>>>(
        h + o5, wqkv, qkv_b, nullptr, nullptr, big, 3 * TD, TD, 0.f, 0);
    hydra_pass1<<<dim3(CH / TT, HCH), blk, 0, stream>>>(big, h + o5, kvp, c * (CH / TT));
  }
  kv_reduce<<<(TB * TD) / 256, blk, 0, stream>>>(kvp, kv);
  wscale_k<<<(TB * TD * TD / 8) / 256, blk, 0, stream>>>(aow, kv, waob);
  gemm_bt<2, 1><<<dim3(M / 128, TD / 128), blk, 0, stream>>>(
      h, waob, aob, resb, resb, nullptr, TD, TD, 1.f, TD * TD);

  // ---- Conv module: PW1+GLU fused (interleaved weights) -> conv -> PW2 ----
  ln_k<0, 1><<<M / 4, blk, 0, stream>>>(resb, lnc_g, lnc_b, h);
  gemm_bt<3, 0><<<dim3(M / 128, 2 * TD / 128), blk, 0, stream>>>(
      h, wpw1g, pw1bg, nullptr, nullptr, big, 2 * TD, TD, 0.f, 0);
  conv6<<<TB * (TT / CT), blk, 0, stream>>>(big, dwt, dw_b, lncn_g, lncn_b, h);
  gemm_bt<2, 1><<<dim3(M / 128, TD / 128), blk, 0, stream>>>(
      h, wpw2, pw2_b, resb, resb, nullptr, TD, TD, 1.f, 0);

  // ---- FF2 (half-step) ----
  ln_k<0, 1><<<M / 4, blk, 0, stream>>>(resb, ln2_g, ln2_b, h);
  for (int c = 0; c < NCHUNK; ++c) {
    const size_t o5 = (size_t)c * CH * TD;
    gemm_bt<1, 0><<<dim3(CH / 128, TDFF / 128), blk, 0, stream>>>(
        h + o5, wff2a, ff2_b1, nullptr, nullptr, big, TDFF, TD, 0.f, 0);
    gemm_bt64<2, 1><<<dim3(CH / 128, TD / 64), blk, 0, stream>>>(
        big, wff2b, ff2_b2, resb + o5, resb + o5, nullptr, TD, TDFF, 0.5f);
  }

  // ---- final LN: d_out(f32) = ln(resb) ----
  ln_k<1, 1><<<M / 4, blk, 0, stream>>>(resb, lno_g, lno_b, d_out);
}